// Round 3
// baseline (34546.271 us; speedup 1.0000x reference)
//
#include <hip/hip_runtime.h>
#include <stdint.h>

// ---------------- constants ----------------
#define NWG   128        // cooperative grid: 1 WG per CU (uses 128 of 256 CUs; L2-broadcast-bound beyond that)
#define NTHR  256
#define Bsz   64
#define Tsz   512
#define Dsz   1024
#define Hsz   1024

typedef __attribute__((ext_vector_type(8))) short short8;   // 8 bf16 (4 VGPRs) — per guide §3
typedef __attribute__((ext_vector_type(4))) float f32x4;

__device__ __forceinline__ unsigned short f2bf(float f) {
    unsigned u = __builtin_bit_cast(unsigned, f);
    u += 0x7fffu + ((u >> 16) & 1u);          // RNE
    return (unsigned short)(u >> 16);
}
__device__ __forceinline__ float bf2f(unsigned short u) {
    return __builtin_bit_cast(float, ((unsigned)u) << 16);
}
__device__ __forceinline__ float sigm(float x) {
    float e = __expf(-__builtin_fabsf(x));
    float r = 1.0f / (1.0f + e);
    return x >= 0.0f ? r : 1.0f - r;          // overflow-safe
}
__device__ __forceinline__ float tanh_(float x) {
    float e = __expf(-2.0f * __builtin_fabsf(x));
    float r = (1.0f - e) / (1.0f + e);
    return x >= 0.0f ? r : -r;                // overflow-safe
}

// ---------------- prep kernels ----------------
// x [B][T][D] f32  ->  xb [t][kb(128)][b(64)][8] bf16   (MFMA A-fragment-native)
__global__ void cast_x(const float* __restrict__ x, unsigned short* __restrict__ xb) {
    int o = blockIdx.x * 256 + threadIdx.x;       // 512*128*64 = 4,194,304
    int t = o >> 13;
    int r = o & 8191;
    int kb = r >> 6;
    int b  = r & 63;
    const float* s = x + (((size_t)b * Tsz + t) * Dsz + kb * 8);
    float4 f0 = ((const float4*)s)[0];
    float4 f1 = ((const float4*)s)[1];
    unsigned short tmp[8];
    tmp[0] = f2bf(f0.x); tmp[1] = f2bf(f0.y); tmp[2] = f2bf(f0.z); tmp[3] = f2bf(f0.w);
    tmp[4] = f2bf(f1.x); tmp[5] = f2bf(f1.y); tmp[6] = f2bf(f1.z); tmp[7] = f2bf(f1.w);
    ((uint4*)xb)[o] = *(const uint4*)tmp;
}

// W [2048][4096] f32 -> wc [w(128)][kb(256)][n(32)][8] bf16 in MFMA B-layout, columns permuted
// so WG w's 32 cols = gates {i,j,f,o} x its 8 h-indices.  col(n) = (n16>>2)*1024 + w*8 + nt*4 + (n16&3)
__global__ void build_wc(const float* __restrict__ W0, const float* __restrict__ W1,
                         unsigned short* __restrict__ wc0, unsigned short* __restrict__ wc1) {
    int o = blockIdx.x * 256 + threadIdx.x;       // 2*128*256*32 = 2,097,152
    int layer = o >> 20;
    int r = o & 1048575;
    int w  = r >> 13;
    int r2 = r & 8191;
    int kb = r2 >> 5;
    int n  = r2 & 31;
    int nt = n >> 4, n16 = n & 15;
    int g = n16 >> 2, q = n16 & 3;
    int col = g * 1024 + w * 8 + nt * 4 + q;
    const float* W = layer ? W1 : W0;
    unsigned short* wc = layer ? wc1 : wc0;
    unsigned short tmp[8];
#pragma unroll
    for (int i = 0; i < 8; ++i) tmp[i] = f2bf(W[(size_t)(kb * 8 + i) * 4096 + col]);
    ((uint4*)wc)[r] = *(const uint4*)tmp;
}

// permuted biases pb[layer][w][32] f32, plus barrier state init (ws is poisoned each launch!)
__global__ void build_pb(const float* __restrict__ b0, const float* __restrict__ b1,
                         float* __restrict__ pb, unsigned* __restrict__ bar) {
    int o = blockIdx.x * 256 + threadIdx.x;       // 8192
    if (o < 2) bar[o] = 0u;
    int layer = o >> 12;
    int r = o & 4095;
    int w = r >> 5;
    int n = r & 31;
    int nt = n >> 4, n16 = n & 15;
    int g = n16 >> 2, q = n16 & 3;
    const float* bb = layer ? b1 : b0;
    pb[o] = bb[g * 1024 + w * 8 + nt * 4 + q];
}

// ---------------- grid barrier (sense-reversing, agent scope) ----------------
__device__ __forceinline__ void gbar(unsigned* bar) {
    __syncthreads();
    if (threadIdx.x == 0) {
        __threadfence();   // release: L2 writeback device-scope
        unsigned g = __hip_atomic_load(&bar[1], __ATOMIC_RELAXED, __HIP_MEMORY_SCOPE_AGENT);
        unsigned v = __hip_atomic_fetch_add(&bar[0], 1u, __ATOMIC_ACQ_REL, __HIP_MEMORY_SCOPE_AGENT);
        if (v == (unsigned)(NWG - 1)) {
            __hip_atomic_store(&bar[0], 0u, __ATOMIC_RELAXED, __HIP_MEMORY_SCOPE_AGENT);
            __hip_atomic_store(&bar[1], g + 1u, __ATOMIC_RELEASE, __HIP_MEMORY_SCOPE_AGENT);
        } else {
            while (__hip_atomic_load(&bar[1], __ATOMIC_ACQUIRE, __HIP_MEMORY_SCOPE_AGENT) == g) {
                __builtin_amdgcn_s_sleep(2);
            }
        }
        __threadfence();   // acquire: L1/L2 invalidate
    }
    __syncthreads();
}

// ---------------- persistent LSTM loop ----------------
// xb  : [t][kb 0..127][b][8] bf16      (layer-0 x part of A)
// y0b : same layout, layer-0 outputs   (layer-1 x part of A)
// hb  : [2 bufs][kb2 0..127][b][8] bf16 (recurrent part of A, double-buffered)
// cst : [2 layers][j 0..1023][b] f32
__launch_bounds__(NTHR)
__global__ void lstm_loop(const unsigned short* __restrict__ xb,
                          unsigned short* __restrict__ y0b,
                          const unsigned short* __restrict__ wc0,
                          const unsigned short* __restrict__ wc1,
                          const float* __restrict__ pb,
                          const int* __restrict__ lens,
                          unsigned short* __restrict__ hb,
                          float* __restrict__ cst,
                          unsigned* __restrict__ bar,
                          float* __restrict__ out) {
    __shared__ float zbuf[2][64][33];   // [k-half][b][col32], +1 pad vs bank conflicts
    __shared__ float pbl[2][32];

    const int w = blockIdx.x;
    const int tid = threadIdx.x;
    const int lane = tid & 63;
    const int wave = tid >> 6;
    const int m  = wave & 1;     // M-pair: rows [m*32, m*32+32)
    const int kh = wave >> 1;    // K-half: 0 = x part, 1 = h part
    const int q16 = lane >> 4;
    const int n16 = lane & 15;

    // ---- per-launch init (ws is re-poisoned every launch) ----
    ((unsigned*)hb)[w * 256 + tid] = 0u;                      // zero hb buf0 slice kb2=w (512 bf16)
    {
        int ly = tid >> 7, r = tid & 127;                     // zero c state rows [8w,8w+8), both layers
        ((float4*)(cst + ly * 65536 + w * 512))[r] = make_float4(0.f, 0.f, 0.f, 0.f);
    }
    if (tid < 64) pbl[tid >> 5][tid & 31] = pb[((tid >> 5) * 128 + w) * 32 + (tid & 31)];
    const int lenb = lens[tid & 63];   // harness passes integer inputs as int32
    gbar(bar);

    for (int layer = 0; layer < 2; ++layer) {
        const unsigned short* xsrc = layer ? y0b : xb;
        const unsigned short* wc   = layer ? wc1 : wc0;
        int p = 0;
        for (int t = 0; t < Tsz; ++t) {
            // ---- GEMM: z[64 x 32cols] += A[64 x 1024(kh)] * W[1024 x 32] ----
            f32x4 a00 = {0.f,0.f,0.f,0.f}, a01 = {0.f,0.f,0.f,0.f};
            f32x4 a10 = {0.f,0.f,0.f,0.f}, a11 = {0.f,0.f,0.f,0.f};
            const unsigned short* Abase = (kh == 0) ? (xsrc + (size_t)t * 65536)
                                                    : (hb + p * 65536);
            const int rowbase = m * 32 + n16;
            const unsigned short* a0p = Abase + (q16 * 64 + rowbase) * 8;
            const unsigned short* a1p = a0p + 128;                     // +16 rows
            const unsigned short* b0p = wc + w * 65536 + (kh * 128 + q16) * 256 + n16 * 8;
            const unsigned short* b1p = b0p + 128;                     // +16 cols
#pragma unroll 4
            for (int s = 0; s < 32; ++s) {
                short8 af0 = *(const short8*)(a0p + s * 2048);
                short8 af1 = *(const short8*)(a1p + s * 2048);
                short8 bf0 = *(const short8*)(b0p + s * 1024);
                short8 bf1 = *(const short8*)(b1p + s * 1024);
                a00 = __builtin_amdgcn_mfma_f32_16x16x32_bf16(af0, bf0, a00, 0, 0, 0);
                a01 = __builtin_amdgcn_mfma_f32_16x16x32_bf16(af0, bf1, a01, 0, 0, 0);
                a10 = __builtin_amdgcn_mfma_f32_16x16x32_bf16(af1, bf0, a10, 0, 0, 0);
                a11 = __builtin_amdgcn_mfma_f32_16x16x32_bf16(af1, bf1, a11, 0, 0, 0);
            }
            {
                const int rowb = m * 32 + q16 * 4;
#pragma unroll
                for (int r = 0; r < 4; ++r) {
                    zbuf[kh][rowb + r][n16]           = a00[r];
                    zbuf[kh][rowb + r][n16 + 16]      = a01[r];
                    zbuf[kh][rowb + 16 + r][n16]      = a10[r];
                    zbuf[kh][rowb + 16 + r][n16 + 16] = a11[r];
                }
            }
            __syncthreads();

            // ---- elementwise gates + state update (this WG owns j = 8w..8w+7) ----
            const int b = tid & 63;
            const bool active = (t < lenb);
#pragma unroll
            for (int h2 = 0; h2 < 2; ++h2) {
                const int jj = (tid >> 6) + h2 * 4;
                const int nt = jj >> 2, qq = jj & 3;
                const int cb = nt * 16 + qq;
                float zi = zbuf[0][b][cb]      + zbuf[1][b][cb]      + pbl[layer][cb];
                float zc = zbuf[0][b][cb + 4]  + zbuf[1][b][cb + 4]  + pbl[layer][cb + 4];
                float zf = zbuf[0][b][cb + 8]  + zbuf[1][b][cb + 8]  + pbl[layer][cb + 8];
                float zo = zbuf[0][b][cb + 12] + zbuf[1][b][cb + 12] + pbl[layer][cb + 12];
                const int ci = (layer * 1024 + w * 8 + jj) * 64 + b;
                const int hi = (w * 64 + b) * 8 + jj;
                unsigned short hv;
                float yv;
                if (active) {
                    float c  = cst[ci];
                    float cn = c * sigm(zf + 1.0f) + sigm(zi) * tanh_(zc);
                    float hn = tanh_(cn) * sigm(zo);
                    cst[ci] = cn;
                    hv = f2bf(hn);
                    yv = hn;
                } else {
                    hv = hb[p * 65536 + hi];   // hold state
                    yv = 0.0f;
                }
                hb[(p ^ 1) * 65536 + hi] = hv;
                if (layer == 0) {
                    y0b[(size_t)t * 65536 + hi] = active ? hv : (unsigned short)0;
                } else {
                    out[(size_t)(b * Tsz + t) * 1024 + w * 8 + jj] = yv;
                }
            }
            gbar(bar);
            p ^= 1;
        }
        // ---- final (h, c) stacks; after 512 steps final h sits in hb buf 0 ----
        {
            const int b = tid & 63;
#pragma unroll
            for (int h2 = 0; h2 < 2; ++h2) {
                const int jj = (tid >> 6) + h2 * 4;
                const int j = w * 8 + jj;
                float hv = bf2f(hb[(w * 64 + b) * 8 + jj]);
                float cv = cst[(layer * 1024 + j) * 64 + b];
                out[33554432 + layer * 65536 + b * 1024 + j]          = hv;   // h_stack
                out[33554432 + 131072 + layer * 65536 + b * 1024 + j] = cv;   // c_stack
            }
        }
        if (layer == 0) {
            // RACE FIX (round 2): extraction above READS hb buf0 across the whole
            // slice from all 4 waves; the re-zero below WRITES that same slice.
            // Without a WG barrier a fast wave's zero-stores can land before a
            // slow wave's extraction loads -> h_stack read as 0 (absmax ~0.88).
            __syncthreads();
            ((unsigned*)hb)[w * 256 + tid] = 0u;   // re-zero hb buf0 (own slice) for layer 1
            gbar(bar);
        }
    }
}

// ---------------- launcher ----------------
extern "C" void kernel_launch(void* const* d_in, const int* in_sizes, int n_in,
                              void* d_out, int out_size, void* d_ws, size_t ws_size,
                              hipStream_t stream) {
    const float* x    = (const float*)d_in[0];
    const int*   lens = (const int*)d_in[1];     // integer inputs arrive as int32
    const float* W0   = (const float*)d_in[2];
    const float* b0   = (const float*)d_in[3];
    const float* W1   = (const float*)d_in[4];
    const float* b1   = (const float*)d_in[5];
    char* ws = (char*)d_ws;

    unsigned short* xb  = (unsigned short*)(ws);                    //  67,108,864 B
    unsigned short* y0b = (unsigned short*)(ws + 67108864);         //  67,108,864 B
    unsigned short* wc0 = (unsigned short*)(ws + 134217728);        //  16,777,216 B
    unsigned short* wc1 = (unsigned short*)(ws + 150994944);        //  16,777,216 B
    float*          pb  = (float*)         (ws + 167772160);        //      32,768 B
    unsigned short* hb  = (unsigned short*)(ws + 167804928);        //     262,144 B
    float*          cst = (float*)         (ws + 168067072);        //     524,288 B
    unsigned*       bar = (unsigned*)      (ws + 168591360);        //         256 B

    hipLaunchKernelGGL(cast_x,   dim3(16384), dim3(256), 0, stream, x, xb);
    hipLaunchKernelGGL(build_wc, dim3(8192),  dim3(256), 0, stream, W0, W1, wc0, wc1);
    hipLaunchKernelGGL(build_pb, dim3(32),    dim3(256), 0, stream, b0, b1, pb, bar);

    float* out = (float*)d_out;
    void* args[] = { &xb, &y0b, &wc0, &wc1, &pb, &lens, &hb, &cst, &bar, &out };
    hipLaunchCooperativeKernel((void*)lstm_loop, dim3(NWG), dim3(NTHR), args, 0, stream);
}